// Round 2
// baseline (86.743 us; speedup 1.0000x reference)
//
#include <hip/hip_runtime.h>

#define N_NODES 50000
#define N_EDGES 640000
#define D 128

typedef float  f4 __attribute__((ext_vector_type(4)));
typedef int    i4 __attribute__((ext_vector_type(4)));

// Kernel 1: one node per 16-lane group, no loop. 3125 blocks x 256 threads
// = 50000 groups, exactly one per node. Lane sl (0..15) loads
// X[n][sl*8 .. sl*8+7] as two float4 (32B/lane, 512B contiguous per node,
// nontemporal: X is streamed once and must not evict s1/s2 from L2).
// Butterfly-reduce over the 16-lane group: 4 steps x 2 dots.
__global__ __launch_bounds__(256) void node_scores_kernel(
    const float* __restrict__ X,
    const float* __restrict__ W1,
    const float* __restrict__ W2,
    float* __restrict__ s1,
    float* __restrict__ s2)
{
    const int lane = threadIdx.x & 63;
    const int sl   = lane & 15;          // lane within 16-lane group
    const int sub  = lane >> 4;          // group within wave (0..3)
    const int wave = blockIdx.x * (blockDim.x >> 6) + (threadIdx.x >> 6);
    const int n    = wave * 4 + sub;     // one node per group
    if (n >= N_NODES) return;

    const f4* W1v = (const f4*)W1;
    const f4* W2v = (const f4*)W2;
    const f4 w1a = W1v[sl * 2],     w1b = W1v[sl * 2 + 1];
    const f4 w2a = W2v[sl * 2],     w2b = W2v[sl * 2 + 1];

    const f4* Xv = (const f4*)(X + (size_t)n * D);
    const f4 x0 = __builtin_nontemporal_load(&Xv[sl * 2]);
    const f4 x1 = __builtin_nontemporal_load(&Xv[sl * 2 + 1]);

    float p1 = x0.x * w1a.x + x0.y * w1a.y + x0.z * w1a.z + x0.w * w1a.w
             + x1.x * w1b.x + x1.y * w1b.y + x1.z * w1b.z + x1.w * w1b.w;
    float p2 = x0.x * w2a.x + x0.y * w2a.y + x0.z * w2a.z + x0.w * w2a.w
             + x1.x * w2b.x + x1.y * w2b.y + x1.z * w2b.z + x1.w * w2b.w;

    // Reduce across the 16-lane group (xor offsets < 16 stay in-group).
    #pragma unroll
    for (int off = 8; off > 0; off >>= 1) {
        p1 += __shfl_xor(p1, off, 64);
        p2 += __shfl_xor(p2, off, 64);
    }
    if (sl == 0) {
        s1[n] = p1;
        s2[n] = p2;
    }
}

// Kernel 2: out[e] = s1[src[e]] + s2[dst[e]]; 4 edges per thread.
// 160000 threads -> 625 blocks of 256 (~10 waves/CU for gather-latency
// hiding). Index streams: int4 coalesced loads; gathers hit the 400KB
// L2-resident tables; output: float4 nontemporal store (no reuse).
__global__ __launch_bounds__(256) void edge_combine_kernel(
    const int* __restrict__ src,
    const int* __restrict__ dst,
    const float* __restrict__ s1,
    const float* __restrict__ s2,
    float* __restrict__ out)
{
    const int i = blockIdx.x * blockDim.x + threadIdx.x;
    if (i < N_EDGES / 4) {
        const i4 s = __builtin_nontemporal_load(&((const i4*)src)[i]);
        const i4 d = __builtin_nontemporal_load(&((const i4*)dst)[i]);
        f4 o;
        o.x = s1[s.x] + s2[d.x];
        o.y = s1[s.y] + s2[d.y];
        o.z = s1[s.z] + s2[d.z];
        o.w = s1[s.w] + s2[d.w];
        __builtin_nontemporal_store(o, &((f4*)out)[i]);
    }
}

extern "C" void kernel_launch(void* const* d_in, const int* in_sizes, int n_in,
                              void* d_out, int out_size, void* d_ws, size_t ws_size,
                              hipStream_t stream) {
    const float* X  = (const float*)d_in[0];   // [N_NODES, D]
    const int*   ei = (const int*)d_in[1];     // [2, N_EDGES] (int32 on device)
    const float* W1 = (const float*)d_in[2];   // [1, D]
    const float* W2 = (const float*)d_in[3];   // [1, D]
    float* out = (float*)d_out;                // [N_EDGES, 1]

    // Workspace: two per-node scalar tables (fully overwritten each call).
    float* s1 = (float*)d_ws;
    float* s2 = s1 + N_NODES;

    // Kernel 1: 3125 blocks x 16 groups = 50000 groups, one node each.
    const int blocks1 = (N_NODES + 15) / 16;   // 3125
    node_scores_kernel<<<blocks1, 256, 0, stream>>>(X, W1, W2, s1, s2);

    // Kernel 2: 160000 threads (4 edges each) -> 625 blocks of 256.
    const int n4 = N_EDGES / 4;                // 160000, exact
    edge_combine_kernel<<<(n4 + 255) / 256, 256, 0, stream>>>(
        ei, ei + N_EDGES, s1, s2, out);
}